// Round 4
// baseline (446.178 us; speedup 1.0000x reference)
//
#include <hip/hip_runtime.h>
#include <hip/hip_bf16.h>

// Problem constants: B,S,D = 2,2048,2048; H=16, HD=128, RD=64, L=512
#define B_ 2
#define S_ 2048
#define D_ 2048
#define H_ 16
#define HD_ 128
#define RD_ 64
#define L_ 512
#define BS_ (B_ * S_)
#define KVH 320
#define QH 192

typedef unsigned short u16;
typedef __bf16 bf16x8 __attribute__((ext_vector_type(8)));
typedef float f32x4 __attribute__((ext_vector_type(4)));
typedef float f32x16 __attribute__((ext_vector_type(16)));
typedef unsigned short us8 __attribute__((ext_vector_type(8)));
typedef unsigned short us4 __attribute__((ext_vector_type(4)));

#define MFMA16(A, B, C) __builtin_amdgcn_mfma_f32_16x16x32_bf16((A), (B), (C), 0, 0, 0)
#define MFMA32(A, B, C) __builtin_amdgcn_mfma_f32_32x32x16_bf16((A), (B), (C), 0, 0, 0)

__device__ __forceinline__ u16 f2bf(float f) {
    unsigned int u = __builtin_bit_cast(unsigned int, f);
    u += 0x7FFFu + ((u >> 16) & 1u);
    return (u16)(u >> 16);
}
__device__ __forceinline__ float bf2f(u16 u) {
    unsigned int x = ((unsigned int)u) << 16;
    return __builtin_bit_cast(float, x);
}
__device__ __forceinline__ void async16(const void* g, void* l) {
    __builtin_amdgcn_global_load_lds((void __attribute__((address_space(1)))*)g,
                                     (void __attribute__((address_space(3)))*)l, 16, 0, 0);
}
__device__ __forceinline__ int swz4(int row) { return (row + (row >> 2)) & 3; }
__device__ __forceinline__ unsigned int cvtpk_bf16(float lo, float hi) {
    unsigned int r;
    asm("v_cvt_pk_bf16_f32 %0, %1, %2" : "=v"(r) : "v"(lo), "v"(hi));
    return r;
}

// ---------------------------------------------------------------------------
// fp32 -> bf16 elementwise (float4 -> us4), n % 1024 == 0
// ---------------------------------------------------------------------------
__global__ __launch_bounds__(256) void conv_f32_bf16(const float* __restrict__ in,
                                                     u16* __restrict__ outp) {
    const int i = blockIdx.x * 256 + threadIdx.x;
    float4 v = *(const float4*)(in + (size_t)i * 4);
    us4 o; o[0] = f2bf(v.x); o[1] = f2bf(v.y); o[2] = f2bf(v.z); o[3] = f2bf(v.w);
    *(us4*)(outp + (size_t)i * 4) = o;
}

// ---------------------------------------------------------------------------
// Transpose + convert: W (K x N) fp32 -> Wt (N x K) bf16.  32x32 tiles.
// ---------------------------------------------------------------------------
__global__ __launch_bounds__(256) void transpose_f32_bf16(const float* __restrict__ W,
                                                          u16* __restrict__ Wt,
                                                          int K, int N) {
    __shared__ float tile[32][33];
    const int t = threadIdx.x, tx = t & 31, ty = t >> 5;
    const int n0 = blockIdx.x * 32, k0 = blockIdx.y * 32;
#pragma unroll
    for (int r = 0; r < 4; r++)
        tile[ty + 8 * r][tx] = W[(size_t)(k0 + ty + 8 * r) * N + n0 + tx];
    __syncthreads();
#pragma unroll
    for (int r = 0; r < 4; r++)
        Wt[(size_t)(n0 + ty + 8 * r) * K + k0 + tx] = f2bf(tile[tx][ty + 8 * r]);
}

// ---------------------------------------------------------------------------
// Extract+transpose V: kv_full (BS x 5120) bf16 -> vtg (B*H, 128, S) bf16
// ---------------------------------------------------------------------------
__global__ __launch_bounds__(256) void transpose_v(const u16* __restrict__ kvf,
                                                   u16* __restrict__ vtg) {
    __shared__ u16 tile[32][33];
    const int t = threadIdx.x, tx = t & 31, ty = t >> 5;
    const int bh = blockIdx.z, b = bh >> 4, h = bh & 15;
    const int s0 = blockIdx.x * 32, d0 = blockIdx.y * 32;
#pragma unroll
    for (int r = 0; r < 4; r++)
        tile[ty + 8 * r][tx] = kvf[(size_t)(b * S_ + s0 + ty + 8 * r) * (H_ * KVH) + h * KVH + QH + d0 + tx];
    __syncthreads();
#pragma unroll
    for (int r = 0; r < 4; r++)
        vtg[((size_t)bh * HD_ + d0 + ty + 8 * r) * S_ + s0 + tx] = tile[tx][ty + 8 * r];
}

// ---------------------------------------------------------------------------
// Fused in-place RoPE on q_full (y=0) and kv_full (y=1)
// ---------------------------------------------------------------------------
__global__ __launch_bounds__(256) void rope_both(u16* __restrict__ qf,
                                                 u16* __restrict__ kvf) {
    const int idx = blockIdx.x * 256 + threadIdx.x;
    const int d = idx & 31;
    const int h = (idx >> 5) & (H_ - 1);
    const int s = (idx >> 9) & (S_ - 1);
    const int b = idx >> 20;
    const int stride = blockIdx.y ? KVH : QH;
    u16* buf = blockIdx.y ? kvf : qf;

    const float inv_freq = powf(10000.0f, -(float)d * (1.0f / 32.0f));
    const float ang = (float)s * inv_freq;
    const float c = cosf(ang), sn = sinf(ang);

    u16* p = buf + ((size_t)((b * S_ + s) * H_) + h) * stride + HD_ + d;
    const float x1 = bf2f(p[0]);
    const float x2 = bf2f(p[32]);
    p[0]  = f2bf(x1 * c - x2 * sn);
    p[32] = f2bf(x2 * c + x1 * sn);
}

// ---------------------------------------------------------------------------
// bf16 MFMA GEMM (m97 structure + swizzled LDS): C = alpha * A (MxK) * Bt^T
// ---------------------------------------------------------------------------
template <int WM, int WN, int TM, int TN, bool OUT_F32>
__global__ __launch_bounds__(WM * WN * 64) void gemm_bf16(
    const u16* __restrict__ A, int lda,
    const u16* __restrict__ Bt, int ldb,
    void* __restrict__ Cv, int ldc, int K, float alpha) {
    constexpr int BMt = WM * TM * 16;
    constexpr int BNt = WN * TN * 16;
    constexpr int NW  = WM * WN;
    constexpr int CA  = BMt / 16;
    constexpr int CB  = BNt / 16;

    __shared__ u16 As[BMt * 32];
    __shared__ u16 Bs[BNt * 32];

    const int t = threadIdx.x, w = t >> 6, l = t & 63;
    const int quad = l >> 4, n16 = l & 15;
    const int wr = w / WN, wc = w % WN;
    const size_t m0 = (size_t)blockIdx.y * BMt;
    const size_t n0 = (size_t)blockIdx.x * BNt;
    const int rowc = l >> 2, sbp = l & 3;

    f32x4 acc[TM][TN];
#pragma unroll
    for (int i = 0; i < TM; i++)
#pragma unroll
        for (int j = 0; j < TN; j++) acc[i][j] = (f32x4){0.f, 0.f, 0.f, 0.f};

    for (int k0 = 0; k0 < K; k0 += 32) {
#pragma unroll
        for (int c = w; c < CA; c += NW) {
            const int row = c * 16 + rowc;
            const int colc = ((sbp - swz4(row)) & 3) * 8;
            async16(A + (m0 + row) * lda + k0 + colc, &As[c * 512 + l * 8]);
        }
#pragma unroll
        for (int c = w; c < CB; c += NW) {
            const int row = c * 16 + rowc;
            const int colc = ((sbp - swz4(row)) & 3) * 8;
            async16(Bt + (n0 + row) * ldb + k0 + colc, &Bs[c * 512 + l * 8]);
        }
        __syncthreads();

        bf16x8 af[TM], bfr[TN];
#pragma unroll
        for (int i = 0; i < TM; i++) {
            const int row = wr * TM * 16 + i * 16 + n16;
            af[i] = *(const bf16x8*)&As[row * 32 + ((quad + swz4(row)) & 3) * 8];
        }
#pragma unroll
        for (int j = 0; j < TN; j++) {
            const int row = wc * TN * 16 + j * 16 + n16;
            bfr[j] = *(const bf16x8*)&Bs[row * 32 + ((quad + swz4(row)) & 3) * 8];
        }
#pragma unroll
        for (int i = 0; i < TM; i++)
#pragma unroll
            for (int j = 0; j < TN; j++) acc[i][j] = MFMA16(af[i], bfr[j], acc[i][j]);
        __syncthreads();
    }

#pragma unroll
    for (int i = 0; i < TM; i++) {
#pragma unroll
        for (int j = 0; j < TN; j++) {
#pragma unroll
            for (int r = 0; r < 4; r++) {
                const size_t row = m0 + wr * TM * 16 + i * 16 + quad * 4 + r;
                const size_t col = n0 + wc * TN * 16 + j * 16 + n16;
                const float v = acc[i][j][r] * alpha;
                if (OUT_F32) ((float*)Cv)[row * ldc + col] = v;
                else         ((u16*)Cv)[row * ldc + col] = f2bf(v);
            }
        }
    }
}

// ---------------------------------------------------------------------------
// Flash MFMA attention v7 — R1 geometry (KV=64, 64KB LDS) with 8 waves/block:
//  * wave (w4, half): w4 = q-subtile (32 rows), half = k-half of the KV-64
//    tile.  Per-CU LDS/MFMA/VALU totals identical to R1, but 2 waves/SIMD
//    at 1 block/CU (4/SIMD if 2 blocks co-reside) -> hides the 12-deep
//    dependent ds_read->MFMA chain that R1 exposed at 1 wave/SIMD.
//  * exact softmax is order-independent -> halves accumulate partial O;
//    merged once per block via LDS (reusing Ks area) + lrun merge.
//  * verified R1 pipeline, counts halved: 3K+2V chunks/wave, vmcnt 5/3
//    steady, 2/0 tail, 3 barriers/tile.
//  * R1's verified K/V 128B-row XOR swizzles and pair-balanced grid kept.
// ---------------------------------------------------------------------------
__global__ __launch_bounds__(512, 1) void attn_mfma(const u16* __restrict__ qf,
                                                    const u16* __restrict__ kvf,
                                                    const u16* __restrict__ vtg,
                                                    u16* __restrict__ ctx) {
    __shared__ u16 Ks[2][3 * 64 * 64];   // 2 x 24576 B
    __shared__ u16 Vs[128 * 64];         // 16384 B

    const int t = threadIdx.x, w = t >> 6, lane = t & 63;
    const int w4 = w & 3, half = w >> 2;
    const int l31 = lane & 31, hi = lane >> 5;

    const int wg = blockIdx.x;
    const int xcd = wg & 7, ii = wg >> 3;
    const int tt = ii & 15;
    const int pp = (tt & 1) ? (tt >> 1) : (15 - (tt >> 1));
    const int qi = (ii & 32) ? (15 - pp) : pp;   // pair-balanced causal order
    const int bh = xcd + 8 * (ii >> 4);
    const int b = bh >> 4, h = bh & 15;
    const int Q0 = qi * 128;

    const u16* Kbase = kvf + (size_t)(b * S_) * (H_ * KVH) + h * KVH;
    const u16* Vbase = vtg + (size_t)bh * HD_ * S_;

    const int scol = ((lane & 7) ^ (lane >> 3)) * 8;  // pre-swizzled src col (u16)
    const int krl  = lane >> 3;                        // row within 8-row chunk

    // hoisted LDS read offsets (static-indexed -> registers)
    int koff[12];
#pragma unroll
    for (int c = 0; c < 12; c++)
        koff[c] = (c >> 2) * 4096 + (((c & 3) * 16 + hi * 8) ^ ((l31 & 7) * 8));
    int voff[2][4];
#pragma unroll
    for (int sl = 0; sl < 2; sl++)
#pragma unroll
        for (int dt = 0; dt < 4; dt++)
            voff[sl][dt] = (dt * 32 + l31) * 64 +
                           (((2 * half + sl) * 16 + hi * 8) ^ ((l31 & 7) * 8));

    // Q fragments (B-operand): col=l31 -> q row Q0+32*w4+l31; k = c*16 + hi*8 + j
    bf16x8 qfrag[12];
    {
        const u16* qr = qf + (size_t)(b * S_ + Q0 + w4 * 32 + l31) * (H_ * QH) + h * QH + hi * 8;
#pragma unroll
        for (int c = 0; c < 12; c++) qfrag[c] = *(const bf16x8*)(qr + c * 16);
    }
    asm volatile("" ::: "memory");   // pin Q loads before async staging (vmcnt order)

    f32x16 O[4];
#pragma unroll
    for (int i = 0; i < 4; i++)
#pragma unroll
        for (int r = 0; r < 16; r++) O[i][r] = 0.f;
    float lrun = 0.f;

    const int qg = Q0 + w4 * 32 + l31;     // this lane's q row (for masking)
    const int qmaxw = Q0 + w4 * 32 + 31;
    const int nkt = 2 * qi + 2;

#define ISSUE_K(KT, BUF)                                                        \
    _Pragma("unroll")                                                           \
    for (int ch = w; ch < 24; ch += 8) {                                        \
        const int c3 = ch >> 3, kq = ch & 7;                                    \
        async16(Kbase + (size_t)((KT) * 64 + kq * 8 + krl) * (H_ * KVH)         \
                      + c3 * 64 + scol,                                         \
                &Ks[BUF][c3 * 4096 + kq * 512 + lane * 8]);                     \
    }
#define ISSUE_V(KT)                                                             \
    _Pragma("unroll")                                                           \
    for (int ch = w; ch < 16; ch += 8) {                                        \
        async16(Vbase + (size_t)(ch * 8 + krl) * S_ + (KT) * 64 + scol,         \
                &Vs[ch * 512 + lane * 8]);                                      \
    }

    ISSUE_K(0, 0);
    ISSUE_V(0);

    for (int kt = 0; kt < nkt; kt++) {
        const int cur = kt & 1;
        if (kt > 0) {
            asm volatile("s_barrier" ::: "memory");            // B1: Vs & Ks[cur^1] free
            ISSUE_V(kt);
        }
        if (kt + 1 < nkt) {
            ISSUE_K(kt + 1, cur ^ 1);
            asm volatile("s_waitcnt vmcnt(5)" ::: "memory");   // K[kt] landed
        } else {
            asm volatile("s_waitcnt vmcnt(2)" ::: "memory");   // K[kt] landed
        }
        asm volatile("s_barrier" ::: "memory");                // B2: all waves' K ready

        const int kb0 = kt * 64 + 32 * half;   // wave's first k in this tile
        const bool active = kb0 <= qmaxw;
        bf16x8 pfrag0, pfrag1;
        if (active) {
            f32x16 sA;                          // S^T half-tile: k rows [kb0, kb0+32)
#pragma unroll
            for (int r = 0; r < 16; r++) sA[r] = 0.f;
            __builtin_amdgcn_s_setprio(1);
#pragma unroll
            for (int c = 0; c < 12; c++) {
                bf16x8 kf = *(const bf16x8*)&Ks[cur][koff[c] + (half * 32 + l31) * 64];
                sA = MFMA32(kf, qfrag[c], sA);
            }
            __builtin_amdgcn_s_setprio(0);

            // exact softmax numerator (Q pre-scaled); causal mask on crossing tiles
            const bool diag = (kb0 + 31) > (Q0 + w4 * 32);
#pragma unroll
            for (int r = 0; r < 16; r++) {
                const int crow = (r & 3) + 8 * (r >> 2) + 4 * hi;
                float pa = exp2f(sA[r]);
                if (diag && (kb0 + crow > qg)) pa = 0.f;
                lrun += pa;
                sA[r] = pa;
            }

            // P -> bf16 A-frags in-register (cvt_pk + permlane32_swap)
            {
                unsigned int x0 = cvtpk_bf16(sA[0], sA[1]);
                unsigned int y0 = cvtpk_bf16(sA[4], sA[5]);
                unsigned int x1 = cvtpk_bf16(sA[2], sA[3]);
                unsigned int y1 = cvtpk_bf16(sA[6], sA[7]);
                asm volatile("v_permlane32_swap_b32 %0, %1" : "+v"(x0), "+v"(y0));
                asm volatile("v_permlane32_swap_b32 %0, %1" : "+v"(x1), "+v"(y1));
                union { unsigned int wv[4]; bf16x8 v; } u_;
                u_.wv[0] = x0; u_.wv[1] = x1; u_.wv[2] = y0; u_.wv[3] = y1;
                pfrag0 = u_.v;
            }
            {
                unsigned int x0 = cvtpk_bf16(sA[8], sA[9]);
                unsigned int y0 = cvtpk_bf16(sA[12], sA[13]);
                unsigned int x1 = cvtpk_bf16(sA[10], sA[11]);
                unsigned int y1 = cvtpk_bf16(sA[14], sA[15]);
                asm volatile("v_permlane32_swap_b32 %0, %1" : "+v"(x0), "+v"(y0));
                asm volatile("v_permlane32_swap_b32 %0, %1" : "+v"(x1), "+v"(y1));
                union { unsigned int wv[4]; bf16x8 v; } u_;
                u_.wv[0] = x0; u_.wv[1] = x1; u_.wv[2] = y0; u_.wv[3] = y1;
                pfrag1 = u_.v;
            }
        }

        if (kt + 1 < nkt) asm volatile("s_waitcnt vmcnt(3)" ::: "memory");  // V[kt] landed
        else              asm volatile("s_waitcnt vmcnt(0)" ::: "memory");
        asm volatile("s_barrier" ::: "memory");                // B3: all waves' V ready

        if (active) {
            __builtin_amdgcn_s_setprio(1);
#pragma unroll
            for (int dt = 0; dt < 4; dt++) {
                bf16x8 vf0 = *(const bf16x8*)&Vs[voff[0][dt]];
                O[dt] = MFMA32(pfrag0, vf0, O[dt]);
                bf16x8 vf1 = *(const bf16x8*)&Vs[voff[1][dt]];
                O[dt] = MFMA32(pfrag1, vf1, O[dt]);
            }
            __builtin_amdgcn_s_setprio(0);
        }
    }
#undef ISSUE_K
#undef ISSUE_V

    // ---- merge the two k-halves via LDS (Ks area is free now) ----
    float* PS = (float*)&Ks[0][0];        // 12288 floats available
    lrun += __shfl_xor(lrun, 32, 64);     // combine hi halves within wave
    if (half) PS[8192 + w4 * 32 + l31] = lrun;
#pragma unroll
    for (int dt = 0; dt < 4; dt++) {
        if (half) {
#pragma unroll
            for (int r = 0; r < 16; r++) PS[w4 * 1024 + lane * 16 + r] = O[dt][r];
        }
        __syncthreads();
        if (!half) {
#pragma unroll
            for (int r = 0; r < 16; r++) O[dt][r] += PS[w4 * 1024 + lane * 16 + r];
        }
        __syncthreads();
    }
    if (half) return;

    const float ltot = lrun + PS[8192 + w4 * 32 + l31];

    // ---- epilogue: redistribute row sums, normalize, store ----
    float inv_[16];
#pragma unroll
    for (int r = 0; r < 16; r++) {
        const int crow = (r & 3) + 8 * (r >> 2) + 4 * hi;
        inv_[r] = 1.0f / __shfl(ltot, crow, 64);
    }
#pragma unroll
    for (int dt = 0; dt < 4; dt++)
#pragma unroll
        for (int r = 0; r < 16; r++) {
            const int crow = (r & 3) + 8 * (r >> 2) + 4 * hi;
            const int qrow = Q0 + w4 * 32 + crow;
            ctx[(size_t)(b * S_ + qrow) * (H_ * HD_) + h * HD_ + dt * 32 + l31] =
                f2bf(O[dt][r] * inv_[r]);
        }
}

// ---------------------------------------------------------------------------
extern "C" void kernel_launch(void* const* d_in, const int* in_sizes, int n_in,
                              void* d_out, int out_size, void* d_ws, size_t ws_size,
                              hipStream_t stream) {
    const float* x         = (const float*)d_in[0];
    const float* w_kv_down = (const float*)d_in[2];
    const float* w_kv_up   = (const float*)d_in[3];
    const float* w_q_down  = (const float*)d_in[4];
    const float* w_q_up    = (const float*)d_in[5];
    const float* w_o       = (const float*)d_in[6];
    float* out = (float*)d_out;

    char* ws = (char*)d_ws;
    size_t off = 0;
    u16* xb      = (u16*)(ws + off); off += (size_t)BS_ * D_ * 2;
    u16* wdt     = (u16*)(ws + off); off += (size_t)1024 * D_ * 2;
    u16* wkvup_t = (u16*)(ws + off); off += (size_t)(H_ * KVH) * L_ * 2;
    u16* wqup_t  = (u16*)(ws + off); off += (size_t)(H_ * QH) * L_ * 2;
    u16* wo_t    = (u16*)(ws + off); off += (size_t)D_ * (H_ * HD_) * 2;
    u16* low     = (u16*)(ws + off); off += (size_t)BS_ * 1024 * 2;
    u16* kv_full = (u16*)(ws + off); off += (size_t)BS_ * H_ * KVH * 2;
    u16* q_full  = (u16*)(ws + off); off += (size_t)BS_ * H_ * QH * 2;
    u16* vtg     = (u16*)(ws + off); off += (size_t)B_ * H_ * HD_ * S_ * 2;
    u16* ctx     = (u16*)(ws + off); off += (size_t)BS_ * H_ * HD_ * 2;

    // softmax scale folded into q_full: log2(e)/sqrt(HD+RD)
    const float qscale = 1.442695041f / 13.856406461f;

    // 0) converts / transposes
    conv_f32_bf16<<<(BS_ * D_) / 1024, 256, 0, stream>>>(x, xb);
    transpose_f32_bf16<<<dim3(L_ / 32, D_ / 32), 256, 0, stream>>>(w_kv_down, wdt, D_, L_);
    transpose_f32_bf16<<<dim3(L_ / 32, D_ / 32), 256, 0, stream>>>(w_q_down, wdt + (size_t)512 * D_, D_, L_);
    transpose_f32_bf16<<<dim3((H_ * KVH) / 32, L_ / 32), 256, 0, stream>>>(w_kv_up, wkvup_t, L_, H_ * KVH);
    transpose_f32_bf16<<<dim3((H_ * QH) / 32, L_ / 32), 256, 0, stream>>>(w_q_up, wqup_t, L_, H_ * QH);
    transpose_f32_bf16<<<dim3(D_ / 32, (H_ * HD_) / 32), 256, 0, stream>>>(w_o, wo_t, H_ * HD_, D_);

    // 1) low = xb @ [w_kv_down | w_q_down]   (4096 x 1024, K=2048)
    gemm_bf16<2, 2, 4, 2, false><<<dim3(1024 / 64, BS_ / 128), 256, 0, stream>>>(
        xb, D_, wdt, D_, low, 1024, D_, 1.0f);
    // 2) kv_full = low[:, :512] @ w_kv_up    (4096 x 5120, K=512)
    gemm_bf16<2, 2, 4, 4, false><<<dim3((H_ * KVH) / 128, BS_ / 128), 256, 0, stream>>>(
        low, 1024, wkvup_t, L_, kv_full, H_ * KVH, L_, 1.0f);
    // 3) q_full = low[:, 512:] @ w_q_up, pre-scaled by log2e/sqrt(192)
    gemm_bf16<2, 2, 4, 4, false><<<dim3((H_ * QH) / 128, BS_ / 128), 256, 0, stream>>>(
        low + 512, 1024, wqup_t, L_, q_full, H_ * QH, L_, qscale);

    // 4) fused RoPE (q_full & kv_full); rotation commutes with the Q pre-scale
    rope_both<<<dim3((B_ * S_ * H_ * 32) / 256, 2), 256, 0, stream>>>(q_full, kv_full);

    // 5) V^T extraction (B*H, 128, S)
    transpose_v<<<dim3(S_ / 32, HD_ / 32, B_ * H_), 256, 0, stream>>>(kv_full, vtg);

    // 6) flash MFMA attention -> ctx (bf16)  [512 blocks x 512 thr, 64KB LDS]
    attn_mfma<<<dim3(512), 512, 0, stream>>>(q_full, kv_full, vtg, ctx);

    // 7) out = ctx @ w_o (fp32 out)          (4096 x 2048, K=2048)
    gemm_bf16<2, 2, 4, 4, true><<<dim3(D_ / 128, BS_ / 128), 256, 0, stream>>>(
        ctx, D_, wo_t, D_, out, D_, D_, 1.0f);
}

// Round 5
// 390.398 us; speedup vs baseline: 1.1429x; 1.1429x over previous
//
#include <hip/hip_runtime.h>
#include <hip/hip_bf16.h>

// Problem constants: B,S,D = 2,2048,2048; H=16, HD=128, RD=64, L=512
#define B_ 2
#define S_ 2048
#define D_ 2048
#define H_ 16
#define HD_ 128
#define RD_ 64
#define L_ 512
#define BS_ (B_ * S_)
#define KVH 320
#define QH 192

typedef unsigned short u16;
typedef __bf16 bf16x8 __attribute__((ext_vector_type(8)));
typedef float f32x4 __attribute__((ext_vector_type(4)));
typedef float f32x16 __attribute__((ext_vector_type(16)));
typedef unsigned short us8 __attribute__((ext_vector_type(8)));
typedef unsigned short us4 __attribute__((ext_vector_type(4)));

#define MFMA16(A, B, C) __builtin_amdgcn_mfma_f32_16x16x32_bf16((A), (B), (C), 0, 0, 0)
#define MFMA32(A, B, C) __builtin_amdgcn_mfma_f32_32x32x16_bf16((A), (B), (C), 0, 0, 0)

__device__ __forceinline__ u16 f2bf(float f) {
    unsigned int u = __builtin_bit_cast(unsigned int, f);
    u += 0x7FFFu + ((u >> 16) & 1u);
    return (u16)(u >> 16);
}
__device__ __forceinline__ float bf2f(u16 u) {
    unsigned int x = ((unsigned int)u) << 16;
    return __builtin_bit_cast(float, x);
}
__device__ __forceinline__ void async16(const void* g, void* l) {
    __builtin_amdgcn_global_load_lds((void __attribute__((address_space(1)))*)g,
                                     (void __attribute__((address_space(3)))*)l, 16, 0, 0);
}
__device__ __forceinline__ int swz4(int row) { return (row + (row >> 2)) & 3; }
__device__ __forceinline__ unsigned int cvtpk_bf16(float lo, float hi) {
    unsigned int r;
    asm("v_cvt_pk_bf16_f32 %0, %1, %2" : "=v"(r) : "v"(lo), "v"(hi));
    return r;
}

// ---------------------------------------------------------------------------
// fp32 -> bf16 elementwise (float4 -> us4), n % 1024 == 0
// ---------------------------------------------------------------------------
__global__ __launch_bounds__(256) void conv_f32_bf16(const float* __restrict__ in,
                                                     u16* __restrict__ outp) {
    const int i = blockIdx.x * 256 + threadIdx.x;
    float4 v = *(const float4*)(in + (size_t)i * 4);
    us4 o; o[0] = f2bf(v.x); o[1] = f2bf(v.y); o[2] = f2bf(v.z); o[3] = f2bf(v.w);
    *(us4*)(outp + (size_t)i * 4) = o;
}

// ---------------------------------------------------------------------------
// Transpose + convert: W (K x N) fp32 -> Wt (N x K) bf16.  32x32 tiles.
// ---------------------------------------------------------------------------
__global__ __launch_bounds__(256) void transpose_f32_bf16(const float* __restrict__ W,
                                                          u16* __restrict__ Wt,
                                                          int K, int N) {
    __shared__ float tile[32][33];
    const int t = threadIdx.x, tx = t & 31, ty = t >> 5;
    const int n0 = blockIdx.x * 32, k0 = blockIdx.y * 32;
#pragma unroll
    for (int r = 0; r < 4; r++)
        tile[ty + 8 * r][tx] = W[(size_t)(k0 + ty + 8 * r) * N + n0 + tx];
    __syncthreads();
#pragma unroll
    for (int r = 0; r < 4; r++)
        Wt[(size_t)(n0 + ty + 8 * r) * K + k0 + tx] = f2bf(tile[tx][ty + 8 * r]);
}

// ---------------------------------------------------------------------------
// Extract+transpose V: kv_full (BS x 5120) bf16 -> vtg (B*H, 128, S) bf16
// 64x64 tiles, 32 B/lane vectorized on both global sides.
// ---------------------------------------------------------------------------
__global__ __launch_bounds__(256) void transpose_v(const u16* __restrict__ kvf,
                                                   u16* __restrict__ vtg) {
    __shared__ u16 tile[64][72];   // 72 stride: 16B-aligned rows
    const int t = threadIdx.x;
    const int r = t >> 2, cb = (t & 3) * 16;
    const int bh = blockIdx.z, b = bh >> 4, h = bh & 15;
    const int s0 = blockIdx.x * 64, d0 = blockIdx.y * 64;

    const u16* src = kvf + (size_t)(b * S_ + s0 + r) * (H_ * KVH) + h * KVH + QH + d0 + cb;
    *(us8*)&tile[r][cb]     = *(const us8*)(src);
    *(us8*)&tile[r][cb + 8] = *(const us8*)(src + 8);
    __syncthreads();

    u16 tmp[16];
#pragma unroll
    for (int j = 0; j < 16; j++) tmp[j] = tile[cb + j][r];
    u16* dst = vtg + ((size_t)bh * HD_ + d0 + r) * S_ + s0 + cb;
    *(us8*)(dst)     = *(us8*)&tmp[0];
    *(us8*)(dst + 8) = *(us8*)&tmp[8];
}

// ---------------------------------------------------------------------------
// RoPE cos/sin table: cs[s*64 + d] = cos(s*invf(d)), cs[s*64+32+d] = sin(...)
// ---------------------------------------------------------------------------
__global__ __launch_bounds__(256) void rope_table(float* __restrict__ cs) {
    const int idx = blockIdx.x * 256 + threadIdx.x;   // 65536 = 2048 s x 32 d
    const int d = idx & 31, s = idx >> 5;
    const float inv_freq = powf(10000.0f, -(float)d * (1.0f / 32.0f));
    const float ang = (float)s * inv_freq;
    cs[s * 64 + d]      = cosf(ang);
    cs[s * 64 + 32 + d] = sinf(ang);
}

// ---------------------------------------------------------------------------
// Fused in-place RoPE on q_full (y=0) and kv_full (y=1); trig from table
// ---------------------------------------------------------------------------
__global__ __launch_bounds__(256) void rope_both(u16* __restrict__ qf,
                                                 u16* __restrict__ kvf,
                                                 const float* __restrict__ cs) {
    const int idx = blockIdx.x * 256 + threadIdx.x;
    const int d = idx & 31;
    const int h = (idx >> 5) & (H_ - 1);
    const int s = (idx >> 9) & (S_ - 1);
    const int b = idx >> 20;
    const int stride = blockIdx.y ? KVH : QH;
    u16* buf = blockIdx.y ? kvf : qf;

    const float c  = cs[s * 64 + d];
    const float sn = cs[s * 64 + 32 + d];

    u16* p = buf + ((size_t)((b * S_ + s) * H_) + h) * stride + HD_ + d;
    const float x1 = bf2f(p[0]);
    const float x2 = bf2f(p[32]);
    p[0]  = f2bf(x1 * c - x2 * sn);
    p[32] = f2bf(x2 * c + x1 * sn);
}

// ---------------------------------------------------------------------------
// bf16 MFMA GEMM (m97 structure + swizzled LDS): C = alpha * A (MxK) * Bt^T
// ---------------------------------------------------------------------------
template <int WM, int WN, int TM, int TN, bool OUT_F32>
__global__ __launch_bounds__(WM * WN * 64) void gemm_bf16(
    const u16* __restrict__ A, int lda,
    const u16* __restrict__ Bt, int ldb,
    void* __restrict__ Cv, int ldc, int K, float alpha) {
    constexpr int BMt = WM * TM * 16;
    constexpr int BNt = WN * TN * 16;
    constexpr int NW  = WM * WN;
    constexpr int CA  = BMt / 16;
    constexpr int CB  = BNt / 16;

    __shared__ u16 As[BMt * 32];
    __shared__ u16 Bs[BNt * 32];

    const int t = threadIdx.x, w = t >> 6, l = t & 63;
    const int quad = l >> 4, n16 = l & 15;
    const int wr = w / WN, wc = w % WN;
    const size_t m0 = (size_t)blockIdx.y * BMt;
    const size_t n0 = (size_t)blockIdx.x * BNt;
    const int rowc = l >> 2, sbp = l & 3;

    f32x4 acc[TM][TN];
#pragma unroll
    for (int i = 0; i < TM; i++)
#pragma unroll
        for (int j = 0; j < TN; j++) acc[i][j] = (f32x4){0.f, 0.f, 0.f, 0.f};

    for (int k0 = 0; k0 < K; k0 += 32) {
#pragma unroll
        for (int c = w; c < CA; c += NW) {
            const int row = c * 16 + rowc;
            const int colc = ((sbp - swz4(row)) & 3) * 8;
            async16(A + (m0 + row) * lda + k0 + colc, &As[c * 512 + l * 8]);
        }
#pragma unroll
        for (int c = w; c < CB; c += NW) {
            const int row = c * 16 + rowc;
            const int colc = ((sbp - swz4(row)) & 3) * 8;
            async16(Bt + (n0 + row) * ldb + k0 + colc, &Bs[c * 512 + l * 8]);
        }
        __syncthreads();

        bf16x8 af[TM], bfr[TN];
#pragma unroll
        for (int i = 0; i < TM; i++) {
            const int row = wr * TM * 16 + i * 16 + n16;
            af[i] = *(const bf16x8*)&As[row * 32 + ((quad + swz4(row)) & 3) * 8];
        }
#pragma unroll
        for (int j = 0; j < TN; j++) {
            const int row = wc * TN * 16 + j * 16 + n16;
            bfr[j] = *(const bf16x8*)&Bs[row * 32 + ((quad + swz4(row)) & 3) * 8];
        }
#pragma unroll
        for (int i = 0; i < TM; i++)
#pragma unroll
            for (int j = 0; j < TN; j++) acc[i][j] = MFMA16(af[i], bfr[j], acc[i][j]);
        __syncthreads();
    }

#pragma unroll
    for (int i = 0; i < TM; i++) {
#pragma unroll
        for (int j = 0; j < TN; j++) {
#pragma unroll
            for (int r = 0; r < 4; r++) {
                const size_t row = m0 + wr * TM * 16 + i * 16 + quad * 4 + r;
                const size_t col = n0 + wc * TN * 16 + j * 16 + n16;
                const float v = acc[i][j][r] * alpha;
                if (OUT_F32) ((float*)Cv)[row * ldc + col] = v;
                else         ((u16*)Cv)[row * ldc + col] = f2bf(v);
            }
        }
    }
}

// ---------------------------------------------------------------------------
// Flash MFMA attention v4 (round-1 verified, 92.6 us) — 32x32x16 MFMA,
// in-register P; only change vs R1: Q is pre-scaled by log2e/sqrt(192) in
// the GEMM epilogue, so exp2f(S) is applied directly (R2-R4-verified math).
// ---------------------------------------------------------------------------
__global__ __launch_bounds__(256, 2) void attn_mfma(const u16* __restrict__ qf,
                                                    const u16* __restrict__ kvf,
                                                    const u16* __restrict__ vtg,
                                                    u16* __restrict__ ctx) {
    __shared__ u16 Ks[2][3 * 64 * 64];   // 2 x 24576 B
    __shared__ u16 Vs[128 * 64];         // 16384 B

    const int t = threadIdx.x, w = t >> 6, lane = t & 63;
    const int l31 = lane & 31, hi = lane >> 5;

    const int wg = blockIdx.x;
    const int xcd = wg & 7, ii = wg >> 3;
    const int tt = ii & 15;
    const int pp = (tt & 1) ? (tt >> 1) : (15 - (tt >> 1));
    const int qi = (ii & 32) ? (15 - pp) : pp;   // pair-balanced causal order
    const int bh = xcd + 8 * (ii >> 4);
    const int b = bh >> 4, h = bh & 15;
    const int Q0 = qi * 128;

    const u16* Kbase = kvf + (size_t)(b * S_) * (H_ * KVH) + h * KVH;
    const u16* Vbase = vtg + (size_t)bh * HD_ * S_;

    const int scol = ((lane & 7) ^ (lane >> 3)) * 8;  // pre-swizzled src col (u16)
    const int krl  = lane >> 3;                        // row within 8-row chunk

    // Q fragments (B-operand): col=l31 -> q row Q0+32w+l31; k = c*16 + hi*8 + j
    bf16x8 qfrag[12];
    {
        const u16* qr = qf + (size_t)(b * S_ + Q0 + w * 32 + l31) * (H_ * QH) + h * QH + hi * 8;
#pragma unroll
        for (int c = 0; c < 12; c++) qfrag[c] = *(const bf16x8*)(qr + c * 16);
    }
    asm volatile("" ::: "memory");   // pin Q loads before async staging (vmcnt order)

    f32x16 O[4];
#pragma unroll
    for (int i = 0; i < 4; i++)
#pragma unroll
        for (int r = 0; r < 16; r++) O[i][r] = 0.f;
    float lrun = 0.f;

    const int qg = Q0 + w * 32 + l31;     // this lane's q row (for masking)
    const int qmaxw = Q0 + w * 32 + 31;
    const int nkt = Q0 / 64 + 2;

#define ISSUE_K(KT, BUF)                                                        \
    _Pragma("unroll")                                                           \
    for (int ch = w; ch < 24; ch += 4) {                                        \
        const int c3 = ch >> 3, kq = ch & 7;                                    \
        async16(Kbase + (size_t)((KT) * 64 + kq * 8 + krl) * (H_ * KVH)         \
                      + c3 * 64 + scol,                                         \
                &Ks[BUF][c3 * 4096 + kq * 512 + lane * 8]);                     \
    }
#define ISSUE_V(KT)                                                             \
    _Pragma("unroll")                                                           \
    for (int ch = w; ch < 16; ch += 4) {                                        \
        async16(Vbase + (size_t)(ch * 8 + krl) * S_ + (KT) * 64 + scol,         \
                &Vs[ch * 512 + lane * 8]);                                      \
    }

    ISSUE_K(0, 0);
    ISSUE_V(0);

    for (int kt = 0; kt < nkt; kt++) {
        const int cur = kt & 1;
        if (kt > 0) {
            asm volatile("s_barrier" ::: "memory");            // B1: Vs & Ks[cur^1] free
            ISSUE_V(kt);
        }
        if (kt + 1 < nkt) {
            ISSUE_K(kt + 1, cur ^ 1);
            asm volatile("s_waitcnt vmcnt(10)" ::: "memory");  // K[kt] landed
        } else {
            asm volatile("s_waitcnt vmcnt(4)" ::: "memory");   // K[kt] landed
        }
        asm volatile("s_barrier" ::: "memory");                // B2: all waves' K ready

        const bool active = (kt * 64) <= qmaxw;
        bf16x8 pfrag[4];
        if (active) {
            const int swz = (l31 & 7) * 8;
            f32x16 sA, sB;                    // S^T tiles: k rows [0,32) / [32,64)
#pragma unroll
            for (int r = 0; r < 16; r++) { sA[r] = 0.f; sB[r] = 0.f; }
            __builtin_amdgcn_s_setprio(1);
#pragma unroll
            for (int c = 0; c < 12; c++) {
                const int cb = (c & 3) * 16 + hi * 8;
                const int base = (c >> 2) * 4096 + (cb ^ swz);
                bf16x8 kf0 = *(const bf16x8*)&Ks[cur][base + l31 * 64];
                bf16x8 kf1 = *(const bf16x8*)&Ks[cur][base + (32 + l31) * 64];
                sA = MFMA32(kf0, qfrag[c], sA);
                sB = MFMA32(kf1, qfrag[c], sB);
            }
            __builtin_amdgcn_s_setprio(0);

            // exact softmax numerator (Q pre-scaled); causal mask on crossing tiles
            const bool diag = (kt * 64 + 63) > (Q0 + w * 32);
#pragma unroll
            for (int r = 0; r < 16; r++) {
                const int crow = (r & 3) + 8 * (r >> 2) + 4 * hi;
                float pa = exp2f(sA[r]);
                float pb = exp2f(sB[r]);
                if (diag) {
                    if (kt * 64 + crow > qg) pa = 0.f;
                    if (kt * 64 + 32 + crow > qg) pb = 0.f;
                }
                lrun += pa + pb;
                sA[r] = pa;
                sB[r] = pb;
            }

            // P -> bf16 A-frags in-register (cvt_pk + permlane32_swap)
#pragma unroll
            for (int s = 0; s < 4; s++) {
                const f32x16 src = (s < 2) ? sA : sB;
                const int r0 = (s & 1) * 8;
                unsigned int x0 = cvtpk_bf16(src[r0 + 0], src[r0 + 1]);
                unsigned int y0 = cvtpk_bf16(src[r0 + 4], src[r0 + 5]);
                unsigned int x1 = cvtpk_bf16(src[r0 + 2], src[r0 + 3]);
                unsigned int y1 = cvtpk_bf16(src[r0 + 6], src[r0 + 7]);
                asm volatile("v_permlane32_swap_b32 %0, %1" : "+v"(x0), "+v"(y0));
                asm volatile("v_permlane32_swap_b32 %0, %1" : "+v"(x1), "+v"(y1));
                union { unsigned int wv[4]; bf16x8 v; } u;
                u.wv[0] = x0; u.wv[1] = x1; u.wv[2] = y0; u.wv[3] = y1;
                pfrag[s] = u.v;
            }
        }

        if (kt + 1 < nkt) asm volatile("s_waitcnt vmcnt(6)" ::: "memory");  // V[kt] landed
        else              asm volatile("s_waitcnt vmcnt(0)" ::: "memory");
        asm volatile("s_barrier" ::: "memory");                // B3: all waves' V ready

        if (active) {
            __builtin_amdgcn_s_setprio(1);
#pragma unroll
            for (int s = 0; s < 4; s++) {
#pragma unroll
                for (int dt = 0; dt < 4; dt++) {
                    const int d = dt * 32 + l31;
                    bf16x8 vf = *(const bf16x8*)&Vs[d * 64 + ((s * 16 + hi * 8) ^ ((d & 7) * 8))];
                    O[dt] = MFMA32(pfrag[s], vf, O[dt]);
                }
            }
            __builtin_amdgcn_s_setprio(0);
        }
    }
#undef ISSUE_K
#undef ISSUE_V

    // ---- epilogue: reduce row-sums over quads, redistribute, store ----
    lrun += __shfl_xor(lrun, 32, 64);     // lane pair (l, l^32) split each q's k-range
    float inv[16];
#pragma unroll
    for (int r = 0; r < 16; r++) {
        const int crow = (r & 3) + 8 * (r >> 2) + 4 * hi;
        inv[r] = 1.0f / __shfl(lrun, crow, 64);
    }
#pragma unroll
    for (int dt = 0; dt < 4; dt++)
#pragma unroll
        for (int r = 0; r < 16; r++) {
            const int crow = (r & 3) + 8 * (r >> 2) + 4 * hi;
            const int qrow = Q0 + w * 32 + crow;
            ctx[(size_t)(b * S_ + qrow) * (H_ * HD_) + h * HD_ + dt * 32 + l31] =
                f2bf(O[dt][r] * inv[r]);
        }
}

// ---------------------------------------------------------------------------
extern "C" void kernel_launch(void* const* d_in, const int* in_sizes, int n_in,
                              void* d_out, int out_size, void* d_ws, size_t ws_size,
                              hipStream_t stream) {
    const float* x         = (const float*)d_in[0];
    const float* w_kv_down = (const float*)d_in[2];
    const float* w_kv_up   = (const float*)d_in[3];
    const float* w_q_down  = (const float*)d_in[4];
    const float* w_q_up    = (const float*)d_in[5];
    const float* w_o       = (const float*)d_in[6];
    float* out = (float*)d_out;

    char* ws = (char*)d_ws;
    size_t off = 0;
    u16* xb      = (u16*)(ws + off); off += (size_t)BS_ * D_ * 2;
    u16* wdt     = (u16*)(ws + off); off += (size_t)1024 * D_ * 2;
    u16* wkvup_t = (u16*)(ws + off); off += (size_t)(H_ * KVH) * L_ * 2;
    u16* wqup_t  = (u16*)(ws + off); off += (size_t)(H_ * QH) * L_ * 2;
    u16* wo_t    = (u16*)(ws + off); off += (size_t)D_ * (H_ * HD_) * 2;
    u16* low     = (u16*)(ws + off); off += (size_t)BS_ * 1024 * 2;
    u16* kv_full = (u16*)(ws + off); off += (size_t)BS_ * H_ * KVH * 2;
    u16* q_full  = (u16*)(ws + off); off += (size_t)BS_ * H_ * QH * 2;
    u16* vtg     = (u16*)(ws + off); off += (size_t)B_ * H_ * HD_ * S_ * 2;
    u16* ctx     = (u16*)(ws + off); off += (size_t)BS_ * H_ * HD_ * 2;
    float* ropecs = (float*)(ws + off); off += (size_t)S_ * 64 * 4;

    // softmax scale folded into q_full: log2(e)/sqrt(HD+RD)
    const float qscale = 1.442695041f / 13.856406461f;

    // 0) converts / transposes / rope table
    rope_table<<<256, 256, 0, stream>>>(ropecs);
    conv_f32_bf16<<<(BS_ * D_) / 1024, 256, 0, stream>>>(x, xb);
    transpose_f32_bf16<<<dim3(L_ / 32, D_ / 32), 256, 0, stream>>>(w_kv_down, wdt, D_, L_);
    transpose_f32_bf16<<<dim3(L_ / 32, D_ / 32), 256, 0, stream>>>(w_q_down, wdt + (size_t)512 * D_, D_, L_);
    transpose_f32_bf16<<<dim3((H_ * KVH) / 32, L_ / 32), 256, 0, stream>>>(w_kv_up, wkvup_t, L_, H_ * KVH);
    transpose_f32_bf16<<<dim3((H_ * QH) / 32, L_ / 32), 256, 0, stream>>>(w_q_up, wqup_t, L_, H_ * QH);
    transpose_f32_bf16<<<dim3(D_ / 32, (H_ * HD_) / 32), 256, 0, stream>>>(w_o, wo_t, H_ * HD_, D_);

    // 1) low = xb @ [w_kv_down | w_q_down]   (4096 x 1024, K=2048)
    gemm_bf16<2, 2, 4, 2, false><<<dim3(1024 / 64, BS_ / 128), 256, 0, stream>>>(
        xb, D_, wdt, D_, low, 1024, D_, 1.0f);
    // 2) kv_full = low[:, :512] @ w_kv_up    (4096 x 5120, K=512)
    gemm_bf16<2, 2, 4, 4, false><<<dim3((H_ * KVH) / 128, BS_ / 128), 256, 0, stream>>>(
        low, 1024, wkvup_t, L_, kv_full, H_ * KVH, L_, 1.0f);
    // 3) q_full = low[:, 512:] @ w_q_up, pre-scaled by log2e/sqrt(192)
    gemm_bf16<2, 2, 4, 4, false><<<dim3((H_ * QH) / 128, BS_ / 128), 256, 0, stream>>>(
        low + 512, 1024, wqup_t, L_, q_full, H_ * QH, L_, qscale);

    // 4) fused RoPE (q_full & kv_full), table-driven
    rope_both<<<dim3((B_ * S_ * H_ * 32) / 256, 2), 256, 0, stream>>>(q_full, kv_full, ropecs);

    // 5) V^T extraction (B*H, 128, S), 64x64 vectorized tiles
    transpose_v<<<dim3(S_ / 64, HD_ / 64, B_ * H_), 256, 0, stream>>>(kv_full, vtg);

    // 6) flash MFMA attention -> ctx (bf16)   [512 blocks: R1-verified kernel]
    attn_mfma<<<dim3(512), 256, 0, stream>>>(q_full, kv_full, vtg, ctx);

    // 7) out = ctx @ w_o (fp32 out)          (4096 x 2048, K=2048)
    gemm_bf16<2, 2, 4, 4, true><<<dim3(D_ / 128, BS_ / 128), 256, 0, stream>>>(
        ctx, D_, wo_t, D_, out, D_, D_, 1.0f);
}

// Round 6
// 382.825 us; speedup vs baseline: 1.1655x; 1.0198x over previous
//
#include <hip/hip_runtime.h>
#include <hip/hip_bf16.h>

// Problem constants: B,S,D = 2,2048,2048; H=16, HD=128, RD=64, L=512
#define B_ 2
#define S_ 2048
#define D_ 2048
#define H_ 16
#define HD_ 128
#define RD_ 64
#define L_ 512
#define BS_ (B_ * S_)
#define KVH 320
#define QH 192

typedef unsigned short u16;
typedef __bf16 bf16x8 __attribute__((ext_vector_type(8)));
typedef float f32x4 __attribute__((ext_vector_type(4)));
typedef float f32x16 __attribute__((ext_vector_type(16)));
typedef unsigned short us8 __attribute__((ext_vector_type(8)));
typedef unsigned short us4 __attribute__((ext_vector_type(4)));

#define MFMA16(A, B, C) __builtin_amdgcn_mfma_f32_16x16x32_bf16((A), (B), (C), 0, 0, 0)
#define MFMA32(A, B, C) __builtin_amdgcn_mfma_f32_32x32x16_bf16((A), (B), (C), 0, 0, 0)

__device__ __forceinline__ u16 f2bf(float f) {
    unsigned int u = __builtin_bit_cast(unsigned int, f);
    u += 0x7FFFu + ((u >> 16) & 1u);
    return (u16)(u >> 16);
}
__device__ __forceinline__ float bf2f(u16 u) {
    unsigned int x = ((unsigned int)u) << 16;
    return __builtin_bit_cast(float, x);
}
__device__ __forceinline__ void async16(const void* g, void* l) {
    __builtin_amdgcn_global_load_lds((void __attribute__((address_space(1)))*)g,
                                     (void __attribute__((address_space(3)))*)l, 16, 0, 0);
}
__device__ __forceinline__ int swz4(int row) { return (row + (row >> 2)) & 3; }
__device__ __forceinline__ unsigned int cvtpk_bf16(float lo, float hi) {
    unsigned int r;
    asm("v_cvt_pk_bf16_f32 %0, %1, %2" : "=v"(r) : "v"(lo), "v"(hi));
    return r;
}

// ---------------------------------------------------------------------------
// fp32 -> bf16 elementwise (float4 -> us4), n % 1024 == 0
// ---------------------------------------------------------------------------
__global__ __launch_bounds__(256) void conv_f32_bf16(const float* __restrict__ in,
                                                     u16* __restrict__ outp) {
    const int i = blockIdx.x * 256 + threadIdx.x;
    float4 v = *(const float4*)(in + (size_t)i * 4);
    us4 o; o[0] = f2bf(v.x); o[1] = f2bf(v.y); o[2] = f2bf(v.z); o[3] = f2bf(v.w);
    *(us4*)(outp + (size_t)i * 4) = o;
}

// ---------------------------------------------------------------------------
// Transpose + convert: W (K x N) fp32 -> Wt (N x K) bf16.  32x32 tiles.
// ---------------------------------------------------------------------------
__global__ __launch_bounds__(256) void transpose_f32_bf16(const float* __restrict__ W,
                                                          u16* __restrict__ Wt,
                                                          int K, int N) {
    __shared__ float tile[32][33];
    const int t = threadIdx.x, tx = t & 31, ty = t >> 5;
    const int n0 = blockIdx.x * 32, k0 = blockIdx.y * 32;
#pragma unroll
    for (int r = 0; r < 4; r++)
        tile[ty + 8 * r][tx] = W[(size_t)(k0 + ty + 8 * r) * N + n0 + tx];
    __syncthreads();
#pragma unroll
    for (int r = 0; r < 4; r++)
        Wt[(size_t)(n0 + ty + 8 * r) * K + k0 + tx] = f2bf(tile[tx][ty + 8 * r]);
}

// ---------------------------------------------------------------------------
// Extract+transpose V: kv_full (BS x 5120) bf16 -> vtg (B*H, 128, S) bf16
// 64x64 tiles, 32 B/lane vectorized on both global sides.
// ---------------------------------------------------------------------------
__global__ __launch_bounds__(256) void transpose_v(const u16* __restrict__ kvf,
                                                   u16* __restrict__ vtg) {
    __shared__ u16 tile[64][72];   // 72 stride: 16B-aligned rows
    const int t = threadIdx.x;
    const int r = t >> 2, cb = (t & 3) * 16;
    const int bh = blockIdx.z, b = bh >> 4, h = bh & 15;
    const int s0 = blockIdx.x * 64, d0 = blockIdx.y * 64;

    const u16* src = kvf + (size_t)(b * S_ + s0 + r) * (H_ * KVH) + h * KVH + QH + d0 + cb;
    *(us8*)&tile[r][cb]     = *(const us8*)(src);
    *(us8*)&tile[r][cb + 8] = *(const us8*)(src + 8);
    __syncthreads();

    u16 tmp[16];
#pragma unroll
    for (int j = 0; j < 16; j++) tmp[j] = tile[cb + j][r];
    u16* dst = vtg + ((size_t)bh * HD_ + d0 + r) * S_ + s0 + cb;
    *(us8*)(dst)     = *(us8*)&tmp[0];
    *(us8*)(dst + 8) = *(us8*)&tmp[8];
}

// ---------------------------------------------------------------------------
// RoPE cos/sin table: cs[s*64 + d] = cos(s*invf(d)), cs[s*64+32+d] = sin(...)
// ---------------------------------------------------------------------------
__global__ __launch_bounds__(256) void rope_table(float* __restrict__ cs) {
    const int idx = blockIdx.x * 256 + threadIdx.x;   // 65536 = 2048 s x 32 d
    const int d = idx & 31, s = idx >> 5;
    const float inv_freq = powf(10000.0f, -(float)d * (1.0f / 32.0f));
    const float ang = (float)s * inv_freq;
    cs[s * 64 + d]      = cosf(ang);
    cs[s * 64 + 32 + d] = sinf(ang);
}

// ---------------------------------------------------------------------------
// Fused in-place RoPE on q_full (y=0) and kv_full (y=1); trig from table
// ---------------------------------------------------------------------------
__global__ __launch_bounds__(256) void rope_both(u16* __restrict__ qf,
                                                 u16* __restrict__ kvf,
                                                 const float* __restrict__ cs) {
    const int idx = blockIdx.x * 256 + threadIdx.x;
    const int d = idx & 31;
    const int h = (idx >> 5) & (H_ - 1);
    const int s = (idx >> 9) & (S_ - 1);
    const int b = idx >> 20;
    const int stride = blockIdx.y ? KVH : QH;
    u16* buf = blockIdx.y ? kvf : qf;

    const float c  = cs[s * 64 + d];
    const float sn = cs[s * 64 + 32 + d];

    u16* p = buf + ((size_t)((b * S_ + s) * H_) + h) * stride + HD_ + d;
    const float x1 = bf2f(p[0]);
    const float x2 = bf2f(p[32]);
    p[0]  = f2bf(x1 * c - x2 * sn);
    p[32] = f2bf(x2 * c + x1 * sn);
}

// ---------------------------------------------------------------------------
// bf16 MFMA GEMM (m97 structure + swizzled LDS): C = alpha * A (MxK) * Bt^T
// T1 XCD-banded grid (1-D): xcd = wg&7 owns 4 A row-bands (2 MB, L2-resident,
// read once); ysub fastest -> 4 co-dispatched blocks share each B-panel.
// Requires M = 4096 (NY = 32 = 8 XCD x 4 bands); grid = 32 * (N/BNt).
// ---------------------------------------------------------------------------
template <int WM, int WN, int TM, int TN, bool OUT_F32>
__global__ __launch_bounds__(WM * WN * 64) void gemm_bf16(
    const u16* __restrict__ A, int lda,
    const u16* __restrict__ Bt, int ldb,
    void* __restrict__ Cv, int ldc, int K, float alpha) {
    constexpr int BMt = WM * TM * 16;
    constexpr int BNt = WN * TN * 16;
    constexpr int NW  = WM * WN;
    constexpr int CA  = BMt / 16;
    constexpr int CB  = BNt / 16;

    __shared__ u16 As[BMt * 32];
    __shared__ u16 Bs[BNt * 32];

    const int t = threadIdx.x, w = t >> 6, l = t & 63;
    const int quad = l >> 4, n16 = l & 15;
    const int wr = w / WN, wc = w % WN;

    // T1: XCD-banded tile assignment (round-robin wg%8 -> XCD, m09/R1-verified)
    const int om = blockIdx.x;
    const int xcd = om & 7, r0_ = om >> 3;
    const int ysub = r0_ & 3, xblk = r0_ >> 2;
    const size_t m0 = (size_t)((xcd << 2) | ysub) * BMt;
    const size_t n0 = (size_t)xblk * BNt;
    const int rowc = l >> 2, sbp = l & 3;

    f32x4 acc[TM][TN];
#pragma unroll
    for (int i = 0; i < TM; i++)
#pragma unroll
        for (int j = 0; j < TN; j++) acc[i][j] = (f32x4){0.f, 0.f, 0.f, 0.f};

    for (int k0 = 0; k0 < K; k0 += 32) {
#pragma unroll
        for (int c = w; c < CA; c += NW) {
            const int row = c * 16 + rowc;
            const int colc = ((sbp - swz4(row)) & 3) * 8;
            async16(A + (m0 + row) * lda + k0 + colc, &As[c * 512 + l * 8]);
        }
#pragma unroll
        for (int c = w; c < CB; c += NW) {
            const int row = c * 16 + rowc;
            const int colc = ((sbp - swz4(row)) & 3) * 8;
            async16(Bt + (n0 + row) * ldb + k0 + colc, &Bs[c * 512 + l * 8]);
        }
        __syncthreads();

        bf16x8 af[TM], bfr[TN];
#pragma unroll
        for (int i = 0; i < TM; i++) {
            const int row = wr * TM * 16 + i * 16 + n16;
            af[i] = *(const bf16x8*)&As[row * 32 + ((quad + swz4(row)) & 3) * 8];
        }
#pragma unroll
        for (int j = 0; j < TN; j++) {
            const int row = wc * TN * 16 + j * 16 + n16;
            bfr[j] = *(const bf16x8*)&Bs[row * 32 + ((quad + swz4(row)) & 3) * 8];
        }
#pragma unroll
        for (int i = 0; i < TM; i++)
#pragma unroll
            for (int j = 0; j < TN; j++) acc[i][j] = MFMA16(af[i], bfr[j], acc[i][j]);
        __syncthreads();
    }

#pragma unroll
    for (int i = 0; i < TM; i++) {
#pragma unroll
        for (int j = 0; j < TN; j++) {
#pragma unroll
            for (int r = 0; r < 4; r++) {
                const size_t row = m0 + wr * TM * 16 + i * 16 + quad * 4 + r;
                const size_t col = n0 + wc * TN * 16 + j * 16 + n16;
                const float v = acc[i][j][r] * alpha;
                if (OUT_F32) ((float*)Cv)[row * ldc + col] = v;
                else         ((u16*)Cv)[row * ldc + col] = f2bf(v);
            }
        }
    }
}

// ---------------------------------------------------------------------------
// Flash MFMA attention v4 (round-1 verified, 90.6 us) — 32x32x16 MFMA,
// in-register P; Q pre-scaled by log2e/sqrt(192) in the GEMM epilogue.
// ---------------------------------------------------------------------------
__global__ __launch_bounds__(256, 2) void attn_mfma(const u16* __restrict__ qf,
                                                    const u16* __restrict__ kvf,
                                                    const u16* __restrict__ vtg,
                                                    u16* __restrict__ ctx) {
    __shared__ u16 Ks[2][3 * 64 * 64];   // 2 x 24576 B
    __shared__ u16 Vs[128 * 64];         // 16384 B

    const int t = threadIdx.x, w = t >> 6, lane = t & 63;
    const int l31 = lane & 31, hi = lane >> 5;

    const int wg = blockIdx.x;
    const int xcd = wg & 7, ii = wg >> 3;
    const int tt = ii & 15;
    const int pp = (tt & 1) ? (tt >> 1) : (15 - (tt >> 1));
    const int qi = (ii & 32) ? (15 - pp) : pp;   // pair-balanced causal order
    const int bh = xcd + 8 * (ii >> 4);
    const int b = bh >> 4, h = bh & 15;
    const int Q0 = qi * 128;

    const u16* Kbase = kvf + (size_t)(b * S_) * (H_ * KVH) + h * KVH;
    const u16* Vbase = vtg + (size_t)bh * HD_ * S_;

    const int scol = ((lane & 7) ^ (lane >> 3)) * 8;  // pre-swizzled src col (u16)
    const int krl  = lane >> 3;                        // row within 8-row chunk

    // Q fragments (B-operand): col=l31 -> q row Q0+32w+l31; k = c*16 + hi*8 + j
    bf16x8 qfrag[12];
    {
        const u16* qr = qf + (size_t)(b * S_ + Q0 + w * 32 + l31) * (H_ * QH) + h * QH + hi * 8;
#pragma unroll
        for (int c = 0; c < 12; c++) qfrag[c] = *(const bf16x8*)(qr + c * 16);
    }
    asm volatile("" ::: "memory");   // pin Q loads before async staging (vmcnt order)

    f32x16 O[4];
#pragma unroll
    for (int i = 0; i < 4; i++)
#pragma unroll
        for (int r = 0; r < 16; r++) O[i][r] = 0.f;
    float lrun = 0.f;

    const int qg = Q0 + w * 32 + l31;     // this lane's q row (for masking)
    const int qmaxw = Q0 + w * 32 + 31;
    const int nkt = Q0 / 64 + 2;

#define ISSUE_K(KT, BUF)                                                        \
    _Pragma("unroll")                                                           \
    for (int ch = w; ch < 24; ch += 4) {                                        \
        const int c3 = ch >> 3, kq = ch & 7;                                    \
        async16(Kbase + (size_t)((KT) * 64 + kq * 8 + krl) * (H_ * KVH)         \
                      + c3 * 64 + scol,                                         \
                &Ks[BUF][c3 * 4096 + kq * 512 + lane * 8]);                     \
    }
#define ISSUE_V(KT)                                                             \
    _Pragma("unroll")                                                           \
    for (int ch = w; ch < 16; ch += 4) {                                        \
        async16(Vbase + (size_t)(ch * 8 + krl) * S_ + (KT) * 64 + scol,         \
                &Vs[ch * 512 + lane * 8]);                                      \
    }

    ISSUE_K(0, 0);
    ISSUE_V(0);

    for (int kt = 0; kt < nkt; kt++) {
        const int cur = kt & 1;
        if (kt > 0) {
            asm volatile("s_barrier" ::: "memory");            // B1: Vs & Ks[1-cur] free
            ISSUE_V(kt);
        }
        if (kt + 1 < nkt) {
            ISSUE_K(kt + 1, cur ^ 1);
            asm volatile("s_waitcnt vmcnt(10)" ::: "memory");  // K[kt] landed
        } else {
            asm volatile("s_waitcnt vmcnt(4)" ::: "memory");   // K[kt] landed
        }
        asm volatile("s_barrier" ::: "memory");                // B2: all waves' K ready

        const bool active = (kt * 64) <= qmaxw;
        bf16x8 pfrag[4];
        if (active) {
            const int swz = (l31 & 7) * 8;
            f32x16 sA, sB;                    // S^T tiles: k rows [0,32) / [32,64)
#pragma unroll
            for (int r = 0; r < 16; r++) { sA[r] = 0.f; sB[r] = 0.f; }
            __builtin_amdgcn_s_setprio(1);
#pragma unroll
            for (int c = 0; c < 12; c++) {
                const int cb = (c & 3) * 16 + hi * 8;
                const int base = (c >> 2) * 4096 + (cb ^ swz);
                bf16x8 kf0 = *(const bf16x8*)&Ks[cur][base + l31 * 64];
                bf16x8 kf1 = *(const bf16x8*)&Ks[cur][base + (32 + l31) * 64];
                sA = MFMA32(kf0, qfrag[c], sA);
                sB = MFMA32(kf1, qfrag[c], sB);
            }
            __builtin_amdgcn_s_setprio(0);

            // exact softmax numerator (Q pre-scaled); causal mask on crossing tiles
            const bool diag = (kt * 64 + 63) > (Q0 + w * 32);
#pragma unroll
            for (int r = 0; r < 16; r++) {
                const int crow = (r & 3) + 8 * (r >> 2) + 4 * hi;
                float pa = exp2f(sA[r]);
                float pb = exp2f(sB[r]);
                if (diag) {
                    if (kt * 64 + crow > qg) pa = 0.f;
                    if (kt * 64 + 32 + crow > qg) pb = 0.f;
                }
                lrun += pa + pb;
                sA[r] = pa;
                sB[r] = pb;
            }

            // P -> bf16 A-frags in-register (cvt_pk + permlane32_swap)
#pragma unroll
            for (int s = 0; s < 4; s++) {
                const f32x16 src = (s < 2) ? sA : sB;
                const int r0 = (s & 1) * 8;
                unsigned int x0 = cvtpk_bf16(src[r0 + 0], src[r0 + 1]);
                unsigned int y0 = cvtpk_bf16(src[r0 + 4], src[r0 + 5]);
                unsigned int x1 = cvtpk_bf16(src[r0 + 2], src[r0 + 3]);
                unsigned int y1 = cvtpk_bf16(src[r0 + 6], src[r0 + 7]);
                asm volatile("v_permlane32_swap_b32 %0, %1" : "+v"(x0), "+v"(y0));
                asm volatile("v_permlane32_swap_b32 %0, %1" : "+v"(x1), "+v"(y1));
                union { unsigned int wv[4]; bf16x8 v; } u;
                u.wv[0] = x0; u.wv[1] = x1; u.wv[2] = y0; u.wv[3] = y1;
                pfrag[s] = u.v;
            }
        }

        if (kt + 1 < nkt) asm volatile("s_waitcnt vmcnt(6)" ::: "memory");  // V[kt] landed
        else              asm volatile("s_waitcnt vmcnt(0)" ::: "memory");
        asm volatile("s_barrier" ::: "memory");                // B3: all waves' V ready

        if (active) {
            __builtin_amdgcn_s_setprio(1);
#pragma unroll
            for (int s = 0; s < 4; s++) {
#pragma unroll
                for (int dt = 0; dt < 4; dt++) {
                    const int d = dt * 32 + l31;
                    bf16x8 vf = *(const bf16x8*)&Vs[d * 64 + ((s * 16 + hi * 8) ^ ((d & 7) * 8))];
                    O[dt] = MFMA32(pfrag[s], vf, O[dt]);
                }
            }
            __builtin_amdgcn_s_setprio(0);
        }
    }
#undef ISSUE_K
#undef ISSUE_V

    // ---- epilogue: reduce row-sums over quads, redistribute, store ----
    lrun += __shfl_xor(lrun, 32, 64);     // lane pair (l, l^32) split each q's k-range
    float inv[16];
#pragma unroll
    for (int r = 0; r < 16; r++) {
        const int crow = (r & 3) + 8 * (r >> 2) + 4 * hi;
        inv[r] = 1.0f / __shfl(lrun, crow, 64);
    }
#pragma unroll
    for (int dt = 0; dt < 4; dt++)
#pragma unroll
        for (int r = 0; r < 16; r++) {
            const int crow = (r & 3) + 8 * (r >> 2) + 4 * hi;
            const int qrow = Q0 + w * 32 + crow;
            ctx[(size_t)(b * S_ + qrow) * (H_ * HD_) + h * HD_ + dt * 32 + l31] =
                f2bf(O[dt][r] * inv[r]);
        }
}

// ---------------------------------------------------------------------------
extern "C" void kernel_launch(void* const* d_in, const int* in_sizes, int n_in,
                              void* d_out, int out_size, void* d_ws, size_t ws_size,
                              hipStream_t stream) {
    const float* x         = (const float*)d_in[0];
    const float* w_kv_down = (const float*)d_in[2];
    const float* w_kv_up   = (const float*)d_in[3];
    const float* w_q_down  = (const float*)d_in[4];
    const float* w_q_up    = (const float*)d_in[5];
    const float* w_o       = (const float*)d_in[6];
    float* out = (float*)d_out;

    char* ws = (char*)d_ws;
    size_t off = 0;
    u16* xb      = (u16*)(ws + off); off += (size_t)BS_ * D_ * 2;
    u16* wdt     = (u16*)(ws + off); off += (size_t)1024 * D_ * 2;
    u16* wkvup_t = (u16*)(ws + off); off += (size_t)(H_ * KVH) * L_ * 2;
    u16* wqup_t  = (u16*)(ws + off); off += (size_t)(H_ * QH) * L_ * 2;
    u16* wo_t    = (u16*)(ws + off); off += (size_t)D_ * (H_ * HD_) * 2;
    u16* low     = (u16*)(ws + off); off += (size_t)BS_ * 1024 * 2;
    u16* kv_full = (u16*)(ws + off); off += (size_t)BS_ * H_ * KVH * 2;
    u16* q_full  = (u16*)(ws + off); off += (size_t)BS_ * H_ * QH * 2;
    u16* vtg     = (u16*)(ws + off); off += (size_t)B_ * H_ * HD_ * S_ * 2;
    u16* ctx     = (u16*)(ws + off); off += (size_t)BS_ * H_ * HD_ * 2;
    float* ropecs = (float*)(ws + off); off += (size_t)S_ * 64 * 4;

    // softmax scale folded into q_full: log2(e)/sqrt(HD+RD)
    const float qscale = 1.442695041f / 13.856406461f;

    // 0) converts / transposes / rope table
    rope_table<<<256, 256, 0, stream>>>(ropecs);
    conv_f32_bf16<<<(BS_ * D_) / 1024, 256, 0, stream>>>(x, xb);
    transpose_f32_bf16<<<dim3(L_ / 32, D_ / 32), 256, 0, stream>>>(w_kv_down, wdt, D_, L_);
    transpose_f32_bf16<<<dim3(L_ / 32, D_ / 32), 256, 0, stream>>>(w_q_down, wdt + (size_t)512 * D_, D_, L_);
    transpose_f32_bf16<<<dim3((H_ * KVH) / 32, L_ / 32), 256, 0, stream>>>(w_kv_up, wkvup_t, L_, H_ * KVH);
    transpose_f32_bf16<<<dim3((H_ * QH) / 32, L_ / 32), 256, 0, stream>>>(w_q_up, wqup_t, L_, H_ * QH);
    transpose_f32_bf16<<<dim3(D_ / 32, (H_ * HD_) / 32), 256, 0, stream>>>(w_o, wo_t, H_ * HD_, D_);

    // 1) low = xb @ [w_kv_down | w_q_down]   (4096 x 1024, K=2048)  [grid 32*NX]
    gemm_bf16<2, 2, 4, 2, false><<<dim3(32 * (1024 / 64)), 256, 0, stream>>>(
        xb, D_, wdt, D_, low, 1024, D_, 1.0f);
    // 2) kv_full = low[:, :512] @ w_kv_up    (4096 x 5120, K=512)
    gemm_bf16<2, 2, 4, 4, false><<<dim3(32 * ((H_ * KVH) / 128)), 256, 0, stream>>>(
        low, 1024, wkvup_t, L_, kv_full, H_ * KVH, L_, 1.0f);
    // 3) q_full = low[:, 512:] @ w_q_up, pre-scaled by log2e/sqrt(192)
    gemm_bf16<2, 2, 4, 4, false><<<dim3(32 * ((H_ * QH) / 128)), 256, 0, stream>>>(
        low + 512, 1024, wqup_t, L_, q_full, H_ * QH, L_, qscale);

    // 4) fused RoPE (q_full & kv_full), table-driven
    rope_both<<<dim3((B_ * S_ * H_ * 32) / 256, 2), 256, 0, stream>>>(q_full, kv_full, ropecs);

    // 5) V^T extraction (B*H, 128, S), 64x64 vectorized tiles
    transpose_v<<<dim3(S_ / 64, HD_ / 64, B_ * H_), 256, 0, stream>>>(kv_full, vtg);

    // 6) flash MFMA attention -> ctx (bf16)   [512 blocks: R1-verified kernel]
    attn_mfma<<<dim3(512), 256, 0, stream>>>(q_full, kv_full, vtg, ctx);

    // 7) out = ctx @ w_o (fp32 out)          (4096 x 2048, K=2048)
    gemm_bf16<2, 2, 4, 4, true><<<dim3(32 * (D_ / 128)), 256, 0, stream>>>(
        ctx, D_, wo_t, D_, out, D_, D_, 1.0f);
}

// Round 7
// 382.808 us; speedup vs baseline: 1.1655x; 1.0000x over previous
//
#include <hip/hip_runtime.h>
#include <hip/hip_bf16.h>

// Problem constants: B,S,D = 2,2048,2048; H=16, HD=128, RD=64, L=512
#define B_ 2
#define S_ 2048
#define D_ 2048
#define H_ 16
#define HD_ 128
#define RD_ 64
#define L_ 512
#define BS_ (B_ * S_)
#define KVH 320
#define QH 192

typedef unsigned short u16;
typedef __bf16 bf16x8 __attribute__((ext_vector_type(8)));
typedef float f32x4 __attribute__((ext_vector_type(4)));
typedef float f32x16 __attribute__((ext_vector_type(16)));
typedef unsigned short us8 __attribute__((ext_vector_type(8)));
typedef unsigned short us4 __attribute__((ext_vector_type(4)));

#define MFMA16(A, B, C) __builtin_amdgcn_mfma_f32_16x16x32_bf16((A), (B), (C), 0, 0, 0)
#define MFMA32(A, B, C) __builtin_amdgcn_mfma_f32_32x32x16_bf16((A), (B), (C), 0, 0, 0)

__device__ __forceinline__ u16 f2bf(float f) {
    unsigned int u = __builtin_bit_cast(unsigned int, f);
    u += 0x7FFFu + ((u >> 16) & 1u);
    return (u16)(u >> 16);
}
__device__ __forceinline__ float bf2f(u16 u) {
    unsigned int x = ((unsigned int)u) << 16;
    return __builtin_bit_cast(float, x);
}
__device__ __forceinline__ void async16(const void* g, void* l) {
    __builtin_amdgcn_global_load_lds((void __attribute__((address_space(1)))*)g,
                                     (void __attribute__((address_space(3)))*)l, 16, 0, 0);
}
__device__ __forceinline__ unsigned int cvtpk_bf16(float lo, float hi) {
    unsigned int r;
    asm("v_cvt_pk_bf16_f32 %0, %1, %2" : "=v"(r) : "v"(lo), "v"(hi));
    return r;
}

// ---------------------------------------------------------------------------
// fp32 -> bf16 elementwise (float4 -> us4), n % 1024 == 0
// ---------------------------------------------------------------------------
__global__ __launch_bounds__(256) void conv_f32_bf16(const float* __restrict__ in,
                                                     u16* __restrict__ outp) {
    const int i = blockIdx.x * 256 + threadIdx.x;
    float4 v = *(const float4*)(in + (size_t)i * 4);
    us4 o; o[0] = f2bf(v.x); o[1] = f2bf(v.y); o[2] = f2bf(v.z); o[3] = f2bf(v.w);
    *(us4*)(outp + (size_t)i * 4) = o;
}

// ---------------------------------------------------------------------------
// Transpose + convert: W (K x N) fp32 -> Wt (N x K) bf16.  32x32 tiles.
// ---------------------------------------------------------------------------
__global__ __launch_bounds__(256) void transpose_f32_bf16(const float* __restrict__ W,
                                                          u16* __restrict__ Wt,
                                                          int K, int N) {
    __shared__ float tile[32][33];
    const int t = threadIdx.x, tx = t & 31, ty = t >> 5;
    const int n0 = blockIdx.x * 32, k0 = blockIdx.y * 32;
#pragma unroll
    for (int r = 0; r < 4; r++)
        tile[ty + 8 * r][tx] = W[(size_t)(k0 + ty + 8 * r) * N + n0 + tx];
    __syncthreads();
#pragma unroll
    for (int r = 0; r < 4; r++)
        Wt[(size_t)(n0 + ty + 8 * r) * K + k0 + tx] = f2bf(tile[tx][ty + 8 * r]);
}

// ---------------------------------------------------------------------------
// Extract+transpose V: kv_full (BS x 5120) bf16 -> vtg (B*H, 128, S) bf16
// 64x64 tiles, 32 B/lane vectorized on both global sides.
// ---------------------------------------------------------------------------
__global__ __launch_bounds__(256) void transpose_v(const u16* __restrict__ kvf,
                                                   u16* __restrict__ vtg) {
    __shared__ u16 tile[64][72];   // 72 stride: 16B-aligned rows
    const int t = threadIdx.x;
    const int r = t >> 2, cb = (t & 3) * 16;
    const int bh = blockIdx.z, b = bh >> 4, h = bh & 15;
    const int s0 = blockIdx.x * 64, d0 = blockIdx.y * 64;

    const u16* src = kvf + (size_t)(b * S_ + s0 + r) * (H_ * KVH) + h * KVH + QH + d0 + cb;
    *(us8*)&tile[r][cb]     = *(const us8*)(src);
    *(us8*)&tile[r][cb + 8] = *(const us8*)(src + 8);
    __syncthreads();

    u16 tmp[16];
#pragma unroll
    for (int j = 0; j < 16; j++) tmp[j] = tile[cb + j][r];
    u16* dst = vtg + ((size_t)bh * HD_ + d0 + r) * S_ + s0 + cb;
    *(us8*)(dst)     = *(us8*)&tmp[0];
    *(us8*)(dst + 8) = *(us8*)&tmp[8];
}

// ---------------------------------------------------------------------------
// RoPE cos/sin table: cs[s*64 + d] = cos(s*invf(d)), cs[s*64+32+d] = sin(...)
// ---------------------------------------------------------------------------
__global__ __launch_bounds__(256) void rope_table(float* __restrict__ cs) {
    const int idx = blockIdx.x * 256 + threadIdx.x;   // 65536 = 2048 s x 32 d
    const int d = idx & 31, s = idx >> 5;
    const float inv_freq = powf(10000.0f, -(float)d * (1.0f / 32.0f));
    const float ang = (float)s * inv_freq;
    cs[s * 64 + d]      = cosf(ang);
    cs[s * 64 + 32 + d] = sinf(ang);
}

// ---------------------------------------------------------------------------
// Fused in-place RoPE on q_full (y=0) and kv_full (y=1); trig from table
// ---------------------------------------------------------------------------
__global__ __launch_bounds__(256) void rope_both(u16* __restrict__ qf,
                                                 u16* __restrict__ kvf,
                                                 const float* __restrict__ cs) {
    const int idx = blockIdx.x * 256 + threadIdx.x;
    const int d = idx & 31;
    const int h = (idx >> 5) & (H_ - 1);
    const int s = (idx >> 9) & (S_ - 1);
    const int b = idx >> 20;
    const int stride = blockIdx.y ? KVH : QH;
    u16* buf = blockIdx.y ? kvf : qf;

    const float c  = cs[s * 64 + d];
    const float sn = cs[s * 64 + 32 + d];

    u16* p = buf + ((size_t)((b * S_ + s) * H_) + h) * stride + HD_ + d;
    const float x1 = bf2f(p[0]);
    const float x2 = bf2f(p[32]);
    p[0]  = f2bf(x1 * c - x2 * sn);
    p[32] = f2bf(x2 * c + x1 * sn);
}

// ---------------------------------------------------------------------------
// gemm256: C = alpha * A (MxK) * Bt^T (Bt NxK), bf16 MFMA, M=4096 fixed.
//  * 128x256 tile, BK=64, 8 waves (2Mx4N), 512 threads; per-wave out 64x64.
//  * Cross-tile pipelined staging (T3/T4 mechanism): tile t+1's 12 async16
//    issued while computing tile t into the OTHER LDS buffer; the only sync
//    is ONE vmcnt(0)-on-stale-loads + ONE s_barrier per 64-deep K-tile.
//    (m97 structure drained vmcnt+2 barriers per 32-K step -> its ~900 TF
//    ceiling; here loads stay in flight across the barrier.)
//  * Race-freedom: staging targets buf^1 whose tile t-1 reads completed
//    before each wave's last MFMA (operand lgkmcnt) which precedes the
//    barrier; in-tile reads touch buf only.
//  * LDS rows 64 bf16-cols (128B) stored as 8 granules of 16B with rotation
//    pos = (g + row&7) & 7; write-side realized by per-lane source-granule
//    pre-rotation (global_load_lds dest stays linear, rule #21).
//  * T1 XCD banding: xcd = wg&7 owns 4 contiguous 128-row A bands.
// ---------------------------------------------------------------------------
template <bool OUT_F32>
__global__ __launch_bounds__(512, 2) void gemm256(
    const u16* __restrict__ A, int lda,
    const u16* __restrict__ Bt, int ldb,
    void* __restrict__ Cv, int ldc, int K, float alpha) {
    __shared__ u16 As[2][128 * 64];   // 2 x 16 KB
    __shared__ u16 Bs[2][256 * 64];   // 2 x 32 KB

    const int t = threadIdx.x, w = t >> 6, lane = t & 63;
    const int quad = lane >> 4, n16 = lane & 15;
    const int wr = w >> 2, wc = w & 3;

    const int wg = blockIdx.x;
    const int xcd = wg & 7, ysub = (wg >> 3) & 3, xblk = wg >> 5;
    const size_t m0 = (size_t)((xcd << 2) | ysub) * 128;
    const size_t n0 = (size_t)xblk * 256;

    // staging: lane l of a chunk writes 16B at (row = 8c + l>>3, pos = l&7);
    // source granule d = (pos - row&7)&7 = ((l&7) - (l>>3))&7  (u16 offset dg)
    const int dg   = ((((lane & 7) - (lane >> 3)) & 7)) * 8;
    const int srow = lane >> 3;
    // read: granule g at row r lives at pos (g + (r&7))&7; r&7 == n16&7 here
    const int posA0 = ((quad + (n16 & 7)) & 7) * 8;        // k-substep 0: g=quad
    const int posA1 = ((quad + 4 + (n16 & 7)) & 7) * 8;    // k-substep 1: g=4+quad

    f32x4 acc[4][4];
#pragma unroll
    for (int i = 0; i < 4; i++)
#pragma unroll
        for (int j = 0; j < 4; j++) acc[i][j] = (f32x4){0.f, 0.f, 0.f, 0.f};

#define STG(K0, BUF)                                                          \
    _Pragma("unroll")                                                         \
    for (int i_ = 0; i_ < 2; i_++) {                                          \
        const int c_ = w + 8 * i_;                                            \
        async16(A + (m0 + c_ * 8 + srow) * lda + (K0) + dg,                   \
                &As[BUF][c_ * 512 + lane * 8]);                               \
    }                                                                         \
    _Pragma("unroll")                                                         \
    for (int i_ = 0; i_ < 4; i_++) {                                          \
        const int c_ = w + 8 * i_;                                            \
        async16(Bt + (n0 + c_ * 8 + srow) * ldb + (K0) + dg,                  \
                &Bs[BUF][c_ * 512 + lane * 8]);                               \
    }

    STG(0, 0)

    const int NT = K / 64;
    for (int tt = 0; tt < NT; tt++) {
        const int cur = tt & 1;
        asm volatile("s_waitcnt vmcnt(0)" ::: "memory");   // own tile-tt loads (stale, cheap)
        asm volatile("s_barrier" ::: "memory");            // all waves' loads landed;
                                                           // closes tile tt-1 reads of buf^1
        // B fragments for the whole tile (kept in regs across all i)
        bf16x8 bfr[4][2];
#pragma unroll
        for (int j = 0; j < 4; j++) {
            const int br = (wc * 64 + j * 16 + n16) * 64;
            bfr[j][0] = *(const bf16x8*)&Bs[cur][br + posA0];
            bfr[j][1] = *(const bf16x8*)&Bs[cur][br + posA1];
        }
        if (tt + 1 < NT) { STG((tt + 1) * 64, cur ^ 1) }   // overlapped prefetch
#pragma unroll
        for (int i = 0; i < 4; i++) {
            const int ar = (wr * 64 + i * 16 + n16) * 64;
            bf16x8 a0 = *(const bf16x8*)&As[cur][ar + posA0];
            bf16x8 a1 = *(const bf16x8*)&As[cur][ar + posA1];
#pragma unroll
            for (int j = 0; j < 4; j++) {
                acc[i][j] = MFMA16(a0, bfr[j][0], acc[i][j]);
                acc[i][j] = MFMA16(a1, bfr[j][1], acc[i][j]);
            }
        }
    }
#undef STG

#pragma unroll
    for (int i = 0; i < 4; i++) {
#pragma unroll
        for (int j = 0; j < 4; j++) {
#pragma unroll
            for (int r = 0; r < 4; r++) {
                const size_t row = m0 + wr * 64 + i * 16 + quad * 4 + r;
                const size_t col = n0 + wc * 64 + j * 16 + n16;
                const float v = acc[i][j][r] * alpha;
                if (OUT_F32) ((float*)Cv)[row * ldc + col] = v;
                else         ((u16*)Cv)[row * ldc + col] = f2bf(v);
            }
        }
    }
}

// ---------------------------------------------------------------------------
// Flash MFMA attention v4 (round-1/5 verified, 90.6 us) — 32x32x16 MFMA,
// in-register P; Q pre-scaled by log2e/sqrt(192) in the GEMM epilogue.
// ---------------------------------------------------------------------------
__global__ __launch_bounds__(256, 2) void attn_mfma(const u16* __restrict__ qf,
                                                    const u16* __restrict__ kvf,
                                                    const u16* __restrict__ vtg,
                                                    u16* __restrict__ ctx) {
    __shared__ u16 Ks[2][3 * 64 * 64];   // 2 x 24576 B
    __shared__ u16 Vs[128 * 64];         // 16384 B

    const int t = threadIdx.x, w = t >> 6, lane = t & 63;
    const int l31 = lane & 31, hi = lane >> 5;

    const int wg = blockIdx.x;
    const int xcd = wg & 7, ii = wg >> 3;
    const int tt = ii & 15;
    const int pp = (tt & 1) ? (tt >> 1) : (15 - (tt >> 1));
    const int qi = (ii & 32) ? (15 - pp) : pp;   // pair-balanced causal order
    const int bh = xcd + 8 * (ii >> 4);
    const int b = bh >> 4, h = bh & 15;
    const int Q0 = qi * 128;

    const u16* Kbase = kvf + (size_t)(b * S_) * (H_ * KVH) + h * KVH;
    const u16* Vbase = vtg + (size_t)bh * HD_ * S_;

    const int scol = ((lane & 7) ^ (lane >> 3)) * 8;  // pre-swizzled src col (u16)
    const int krl  = lane >> 3;                        // row within 8-row chunk

    // Q fragments (B-operand): col=l31 -> q row Q0+32w+l31; k = c*16 + hi*8 + j
    bf16x8 qfrag[12];
    {
        const u16* qr = qf + (size_t)(b * S_ + Q0 + w * 32 + l31) * (H_ * QH) + h * QH + hi * 8;
#pragma unroll
        for (int c = 0; c < 12; c++) qfrag[c] = *(const bf16x8*)(qr + c * 16);
    }
    asm volatile("" ::: "memory");   // pin Q loads before async staging (vmcnt order)

    f32x16 O[4];
#pragma unroll
    for (int i = 0; i < 4; i++)
#pragma unroll
        for (int r = 0; r < 16; r++) O[i][r] = 0.f;
    float lrun = 0.f;

    const int qg = Q0 + w * 32 + l31;     // this lane's q row (for masking)
    const int qmaxw = Q0 + w * 32 + 31;
    const int nkt = Q0 / 64 + 2;

#define ISSUE_K(KT, BUF)                                                        \
    _Pragma("unroll")                                                           \
    for (int ch = w; ch < 24; ch += 4) {                                        \
        const int c3 = ch >> 3, kq = ch & 7;                                    \
        async16(Kbase + (size_t)((KT) * 64 + kq * 8 + krl) * (H_ * KVH)         \
                      + c3 * 64 + scol,                                         \
                &Ks[BUF][c3 * 4096 + kq * 512 + lane * 8]);                     \
    }
#define ISSUE_V(KT)                                                             \
    _Pragma("unroll")                                                           \
    for (int ch = w; ch < 16; ch += 4) {                                        \
        async16(Vbase + (size_t)(ch * 8 + krl) * S_ + (KT) * 64 + scol,         \
                &Vs[ch * 512 + lane * 8]);                                      \
    }

    ISSUE_K(0, 0);
    ISSUE_V(0);

    for (int kt = 0; kt < nkt; kt++) {
        const int cur = kt & 1;
        if (kt > 0) {
            asm volatile("s_barrier" ::: "memory");            // B1: Vs & Ks[1-cur] free
            ISSUE_V(kt);
        }
        if (kt + 1 < nkt) {
            ISSUE_K(kt + 1, cur ^ 1);
            asm volatile("s_waitcnt vmcnt(10)" ::: "memory");  // K[kt] landed
        } else {
            asm volatile("s_waitcnt vmcnt(4)" ::: "memory");   // K[kt] landed
        }
        asm volatile("s_barrier" ::: "memory");                // B2: all waves' K ready

        const bool active = (kt * 64) <= qmaxw;
        bf16x8 pfrag[4];
        if (active) {
            const int swz = (l31 & 7) * 8;
            f32x16 sA, sB;                    // S^T tiles: k rows [0,32) / [32,64)
#pragma unroll
            for (int r = 0; r < 16; r++) { sA[r] = 0.f; sB[r] = 0.f; }
            __builtin_amdgcn_s_setprio(1);
#pragma unroll
            for (int c = 0; c < 12; c++) {
                const int cb = (c & 3) * 16 + hi * 8;
                const int base = (c >> 2) * 4096 + (cb ^ swz);
                bf16x8 kf0 = *(const bf16x8*)&Ks[cur][base + l31 * 64];
                bf16x8 kf1 = *(const bf16x8*)&Ks[cur][base + (32 + l31) * 64];
                sA = MFMA32(kf0, qfrag[c], sA);
                sB = MFMA32(kf1, qfrag[c], sB);
            }
            __builtin_amdgcn_s_setprio(0);

            // exact softmax numerator (Q pre-scaled); causal mask on crossing tiles
            const bool diag = (kt * 64 + 63) > (Q0 + w * 32);
#pragma unroll
            for (int r = 0; r < 16; r++) {
                const int crow = (r & 3) + 8 * (r >> 2) + 4 * hi;
                float pa = exp2f(sA[r]);
                float pb = exp2f(sB[r]);
                if (diag) {
                    if (kt * 64 + crow > qg) pa = 0.f;
                    if (kt * 64 + 32 + crow > qg) pb = 0.f;
                }
                lrun += pa + pb;
                sA[r] = pa;
                sB[r] = pb;
            }

            // P -> bf16 A-frags in-register (cvt_pk + permlane32_swap)
#pragma unroll
            for (int s = 0; s < 4; s++) {
                const f32x16 src = (s < 2) ? sA : sB;
                const int r0 = (s & 1) * 8;
                unsigned int x0 = cvtpk_bf16(src[r0 + 0], src[r0 + 1]);
                unsigned int y0 = cvtpk_bf16(src[r0 + 4], src[r0 + 5]);
                unsigned int x1 = cvtpk_bf16(src[r0 + 2], src[r0 + 3]);
                unsigned int y1 = cvtpk_bf16(src[r0 + 6], src[r0 + 7]);
                asm volatile("v_permlane32_swap_b32 %0, %1" : "+v"(x0), "+v"(y0));
                asm volatile("v_permlane32_swap_b32 %0, %1" : "+v"(x1), "+v"(y1));
                union { unsigned int wv[4]; bf16x8 v; } u;
                u.wv[0] = x0; u.wv[1] = x1; u.wv[2] = y0; u.wv[3] = y1;
                pfrag[s] = u.v;
            }
        }

        if (kt + 1 < nkt) asm volatile("s_waitcnt vmcnt(6)" ::: "memory");  // V[kt] landed
        else              asm volatile("s_waitcnt vmcnt(0)" ::: "memory");
        asm volatile("s_barrier" ::: "memory");                // B3: all waves' V ready

        if (active) {
            __builtin_amdgcn_s_setprio(1);
#pragma unroll
            for (int s = 0; s < 4; s++) {
#pragma unroll
                for (int dt = 0; dt < 4; dt++) {
                    const int d = dt * 32 + l31;
                    bf16x8 vf = *(const bf16x8*)&Vs[d * 64 + ((s * 16 + hi * 8) ^ ((d & 7) * 8))];
                    O[dt] = MFMA32(pfrag[s], vf, O[dt]);
                }
            }
            __builtin_amdgcn_s_setprio(0);
        }
    }
#undef ISSUE_K
#undef ISSUE_V

    // ---- epilogue: reduce row-sums over quads, redistribute, store ----
    lrun += __shfl_xor(lrun, 32, 64);     // lane pair (l, l^32) split each q's k-range
    float inv[16];
#pragma unroll
    for (int r = 0; r < 16; r++) {
        const int crow = (r & 3) + 8 * (r >> 2) + 4 * hi;
        inv[r] = 1.0f / __shfl(lrun, crow, 64);
    }
#pragma unroll
    for (int dt = 0; dt < 4; dt++)
#pragma unroll
        for (int r = 0; r < 16; r++) {
            const int crow = (r & 3) + 8 * (r >> 2) + 4 * hi;
            const int qrow = Q0 + w * 32 + crow;
            ctx[(size_t)(b * S_ + qrow) * (H_ * HD_) + h * HD_ + dt * 32 + l31] =
                f2bf(O[dt][r] * inv[r]);
        }
}

// ---------------------------------------------------------------------------
extern "C" void kernel_launch(void* const* d_in, const int* in_sizes, int n_in,
                              void* d_out, int out_size, void* d_ws, size_t ws_size,
                              hipStream_t stream) {
    const float* x         = (const float*)d_in[0];
    const float* w_kv_down = (const float*)d_in[2];
    const float* w_kv_up   = (const float*)d_in[3];
    const float* w_q_down  = (const float*)d_in[4];
    const float* w_q_up    = (const float*)d_in[5];
    const float* w_o       = (const float*)d_in[6];
    float* out = (float*)d_out;

    char* ws = (char*)d_ws;
    size_t off = 0;
    u16* xb      = (u16*)(ws + off); off += (size_t)BS_ * D_ * 2;
    u16* wdt     = (u16*)(ws + off); off += (size_t)1024 * D_ * 2;
    u16* wkvup_t = (u16*)(ws + off); off += (size_t)(H_ * KVH) * L_ * 2;
    u16* wqup_t  = (u16*)(ws + off); off += (size_t)(H_ * QH) * L_ * 2;
    u16* wo_t    = (u16*)(ws + off); off += (size_t)D_ * (H_ * HD_) * 2;
    u16* low     = (u16*)(ws + off); off += (size_t)BS_ * 1024 * 2;
    u16* kv_full = (u16*)(ws + off); off += (size_t)BS_ * H_ * KVH * 2;
    u16* q_full  = (u16*)(ws + off); off += (size_t)BS_ * H_ * QH * 2;
    u16* vtg     = (u16*)(ws + off); off += (size_t)B_ * H_ * HD_ * S_ * 2;
    u16* ctx     = (u16*)(ws + off); off += (size_t)BS_ * H_ * HD_ * 2;
    float* ropecs = (float*)(ws + off); off += (size_t)S_ * 64 * 4;

    // softmax scale folded into q_full: log2(e)/sqrt(HD+RD)
    const float qscale = 1.442695041f / 13.856406461f;

    // 0) converts / transposes / rope table
    rope_table<<<256, 256, 0, stream>>>(ropecs);
    conv_f32_bf16<<<(BS_ * D_) / 1024, 256, 0, stream>>>(x, xb);
    transpose_f32_bf16<<<dim3(L_ / 32, D_ / 32), 256, 0, stream>>>(w_kv_down, wdt, D_, L_);
    transpose_f32_bf16<<<dim3(L_ / 32, D_ / 32), 256, 0, stream>>>(w_q_down, wdt + (size_t)512 * D_, D_, L_);
    transpose_f32_bf16<<<dim3((H_ * KVH) / 32, L_ / 32), 256, 0, stream>>>(w_kv_up, wkvup_t, L_, H_ * KVH);
    transpose_f32_bf16<<<dim3((H_ * QH) / 32, L_ / 32), 256, 0, stream>>>(w_q_up, wqup_t, L_, H_ * QH);
    transpose_f32_bf16<<<dim3(D_ / 32, (H_ * HD_) / 32), 256, 0, stream>>>(w_o, wo_t, H_ * HD_, D_);

    // 1) low = xb @ [w_kv_down | w_q_down]   (4096 x 1024, K=2048)  grid 32*4
    gemm256<false><<<dim3(32 * (1024 / 256)), 512, 0, stream>>>(
        xb, D_, wdt, D_, low, 1024, D_, 1.0f);
    // 2) kv_full = low[:, :512] @ w_kv_up    (4096 x 5120, K=512)   grid 32*20
    gemm256<false><<<dim3(32 * ((H_ * KVH) / 256)), 512, 0, stream>>>(
        low, 1024, wkvup_t, L_, kv_full, H_ * KVH, L_, 1.0f);
    // 3) q_full = low[:, 512:] @ w_q_up (pre-scaled)  (4096 x 3072, K=512)  grid 32*12
    gemm256<false><<<dim3(32 * ((H_ * QH) / 256)), 512, 0, stream>>>(
        low + 512, 1024, wqup_t, L_, q_full, H_ * QH, L_, qscale);

    // 4) fused RoPE (q_full & kv_full), table-driven
    rope_both<<<dim3((B_ * S_ * H_ * 32) / 256, 2), 256, 0, stream>>>(q_full, kv_full, ropecs);

    // 5) V^T extraction (B*H, 128, S), 64x64 vectorized tiles
    transpose_v<<<dim3(S_ / 64, HD_ / 64, B_ * H_), 256, 0, stream>>>(kv_full, vtg);

    // 6) flash MFMA attention -> ctx (bf16)   [512 blocks: R1-verified kernel]
    attn_mfma<<<dim3(512), 256, 0, stream>>>(q_full, kv_full, vtg, ctx);

    // 7) out = ctx @ w_o (fp32 out)          (4096 x 2048, K=2048)  grid 32*8
    gemm256<true><<<dim3(32 * (D_ / 256)), 512, 0, stream>>>(
        ctx, D_, wo_t, D_, out, D_, D_, 1.0f);
}